// Round 15
// baseline (188.114 us; speedup 1.0000x reference)
//
#include <hip/hip_runtime.h>

#define TT 52          // tag count incl START/STOP
#define NT 50          // normal tags
#define START_TAG 50
#define STOP_TAG 51
#define BB 1024
#define SS 512
#define BPSTR 64       // fallback kernel LDS bp row stride

#if __has_builtin(__builtin_amdgcn_permlane32_swap) && __has_builtin(__builtin_amdgcn_permlane16_swap)
#define HAVE_SWAPS 1
#else
#define HAVE_SWAPS 0
#endif

__device__ __forceinline__ int seq_len(const void* mask, int b, int j) {
    int cnt = 0;
    const unsigned* w = (const unsigned*)mask;
    unsigned w0 = w[0];
    unsigned w1 = w[1];
    if (w0 == 0x01010101u) {                       // bool / uint8
        const unsigned char* m = (const unsigned char*)mask + (size_t)b * SS;
        for (int k = j; k < SS; k += 64) cnt += (m[k] != 0);
    } else if (w0 == 0x3f800000u) {                // float32
        const float* m = (const float*)mask + (size_t)b * SS;
        for (int k = j; k < SS; k += 64) cnt += (m[k] != 0.f);
    } else if (w1 == 1u) {                         // int32
        const int* m = (const int*)mask + (size_t)b * SS;
        for (int k = j; k < SS; k += 64) cnt += (m[k] != 0);
    } else {                                       // int64
        const long long* m = (const long long*)mask + (size_t)b * SS;
        for (int k = j; k < SS; k += 64) cnt += (m[k] != 0);
    }
    for (int off = 32; off; off >>= 1) cnt += __shfl_xor(cnt, off, 64);
    return cnt > 0 ? cnt : 1;
}

// ---- fused gather+add: one v_add_f32 with DPP row_ror:K on src0 ------------
// Same permutation as __builtin_amdgcn_mov_dpp(ctrl=0x120|K) used by the
// calibration probe (row_ror is a full within-row rotation; exec all-on, so
// bound_ctrl/masks are irrelevant). 1 instruction per candidate.
#define RRA(R, K, BRF)                                                            \
    asm("v_add_f32 %0, %1, %2 row_ror:" #K                                        \
        : "=v"(s_[16 * (R) + (K)]) : "v"(BRF), "v"(tt_[R][K]));

#define EXPAND16A(R, BRF)                                                         \
    s_[16 * (R) + 0] = (BRF) + tt_[R][0];                                         \
    RRA(R, 1, BRF)  RRA(R, 2, BRF)  RRA(R, 3, BRF)  RRA(R, 4, BRF)               \
    RRA(R, 5, BRF)  RRA(R, 6, BRF)  RRA(R, 7, BRF)  RRA(R, 8, BRF)               \
    RRA(R, 9, BRF)  RRA(R, 10, BRF) RRA(R, 11, BRF) RRA(R, 12, BRF)              \
    RRA(R, 13, BRF) RRA(R, 14, BRF) RRA(R, 15, BRF)

#define PR(R, K, BREG)                                                            \
    src_[R][K] = __builtin_amdgcn_mov_dpp((BREG), 0x120 | (K), 0xF, 0xF, true) & 63;

#define PROBE16(R, BREG)                                                          \
    src_[R][0] = (BREG) & 63;                                                     \
    PR(R, 1, BREG)  PR(R, 2, BREG)  PR(R, 3, BREG)  PR(R, 4, BREG)               \
    PR(R, 5, BREG)  PR(R, 6, BREG)  PR(R, 7, BREG)  PR(R, 8, BREG)               \
    PR(R, 9, BREG)  PR(R, 10, BREG) PR(R, 11, BREG) PR(R, 12, BREG)              \
    PR(R, 13, BREG) PR(R, 14, BREG) PR(R, 15, BREG)

// exact max tree over s_[64] -> bv_ (order-independent, v_max3-friendly)
#define MAXTREE                                                                   \
    float m_[21];                                                                 \
    _Pragma("unroll")                                                             \
    for (int q_ = 0; q_ < 21; ++q_)                                               \
        m_[q_] = fmaxf(fmaxf(s_[3 * q_], s_[3 * q_ + 1]), s_[3 * q_ + 2]);        \
    float n_[7];                                                                  \
    _Pragma("unroll")                                                             \
    for (int q_ = 0; q_ < 7; ++q_)                                                \
        n_[q_] = fmaxf(fmaxf(m_[3 * q_], m_[3 * q_ + 1]), m_[3 * q_ + 2]);        \
    float t0_ = fmaxf(fmaxf(n_[0], n_[1]), n_[2]);                                \
    float t1_ = fmaxf(fmaxf(n_[3], n_[4]), n_[5]);                                \
    float t2_ = fmaxf(n_[6], s_[63]);                                             \
    float bv_ = fmaxf(fmaxf(t0_, t1_), t2_);

#if HAVE_SWAPS
// all-VALU step: 3 permlane swaps -> 4 row-broadcast regs; 64 adds (60 with
// fused DPP gather); exact tree; store bv; alpha = bv + f.
#define DP_STEP_FAST(FREG, POSV)                                                  \
    {                                                                             \
        const unsigned a_ = __builtin_bit_cast(unsigned, alpha);                  \
        auto pp_ = __builtin_amdgcn_permlane32_swap(a_, a_, false, false);        \
        auto q0_ = __builtin_amdgcn_permlane16_swap(pp_[0], pp_[0], false, false);\
        auto q1_ = __builtin_amdgcn_permlane16_swap(pp_[1], pp_[1], false, false);\
        const float F0_ = __builtin_bit_cast(float, (unsigned)q0_[0]);            \
        const float F1_ = __builtin_bit_cast(float, (unsigned)q0_[1]);            \
        const float F2_ = __builtin_bit_cast(float, (unsigned)q1_[0]);            \
        const float F3_ = __builtin_bit_cast(float, (unsigned)q1_[1]);            \
        float s_[64];                                                             \
        EXPAND16A(0, F0_) EXPAND16A(1, F1_) EXPAND16A(2, F2_) EXPAND16A(3, F3_)   \
        MAXTREE                                                                   \
        wsb[(size_t)(POSV) * 64] = bv_;                                           \
        alpha = bv_ + (FREG);                                                     \
    }
#endif

// r9 LDS-broadcast step (proven path) — runtime/compile fallback
#define DP_STEP_LDS(FREG, POSV)                                                   \
    {                                                                             \
        a_sh[j] = alpha;                                                          \
        const float4* A4_ = (const float4*)a_sh;                                  \
        float q_[52];                                                             \
        _Pragma("unroll")                                                         \
        for (int r_ = 0; r_ < 13; ++r_) {                                         \
            float4 t4_ = A4_[r_];                                                 \
            q_[4 * r_ + 0] = t4_.x; q_[4 * r_ + 1] = t4_.y;                       \
            q_[4 * r_ + 2] = t4_.z; q_[4 * r_ + 3] = t4_.w;                       \
        }                                                                         \
        float sl_[NT];                                                            \
        _Pragma("unroll")                                                         \
        for (int i_ = 0; i_ < NT; ++i_) sl_[i_] = q_[i_] + tt[i_];                \
        float ml_[17];                                                            \
        _Pragma("unroll")                                                         \
        for (int k_ = 0; k_ < 16; ++k_)                                           \
            ml_[k_] = fmaxf(fmaxf(sl_[3 * k_], sl_[3 * k_ + 1]), sl_[3 * k_ + 2]);\
        ml_[16] = fmaxf(sl_[48], sl_[49]);                                        \
        float nl_[6];                                                             \
        _Pragma("unroll")                                                         \
        for (int k_ = 0; k_ < 5; ++k_)                                            \
            nl_[k_] = fmaxf(fmaxf(ml_[3 * k_], ml_[3 * k_ + 1]), ml_[3 * k_ + 2]);\
        nl_[5] = fmaxf(ml_[15], ml_[16]);                                         \
        float q0l_ = fmaxf(fmaxf(nl_[0], nl_[1]), nl_[2]);                        \
        float q1l_ = fmaxf(fmaxf(nl_[3], nl_[4]), nl_[5]);                        \
        float bv_ = fmaxf(q0l_, q1l_);                                            \
        wsb[(size_t)(POSV) * 64] = bv_;                                           \
        alpha = bv_ + (FREG);                                                     \
    }

// clamped feats load for lane's own tag (jc) at position p
#define FLD(P) fp[(size_t)((P) < SS ? (P) : SS - 1) * TT]

// forward loop skeleton: 8-deep prefetch, unroll-8, tail
#define FWD_LOOP(STEP)                                                            \
    {                                                                             \
        float fA0 = FLD(1), fA1 = FLD(2), fA2 = FLD(3), fA3 = FLD(4);             \
        float fB0 = FLD(5), fB1 = FLD(6), fB2 = FLD(7), fB3 = FLD(8);             \
        int pos = 1;                                                              \
        for (; pos + 7 < len; pos += 8) {                                         \
            STEP(fA0, pos + 0)                                                    \
            STEP(fA1, pos + 1)                                                    \
            STEP(fA2, pos + 2)                                                    \
            STEP(fA3, pos + 3)                                                    \
            fA0 = FLD(pos + 8);  fA1 = FLD(pos + 9);                              \
            fA2 = FLD(pos + 10); fA3 = FLD(pos + 11);                             \
            STEP(fB0, pos + 4)                                                    \
            STEP(fB1, pos + 5)                                                    \
            STEP(fB2, pos + 6)                                                    \
            STEP(fB3, pos + 7)                                                    \
            fB0 = FLD(pos + 12); fB1 = FLD(pos + 13);                             \
            fB2 = FLD(pos + 14); fB3 = FLD(pos + 15);                             \
        }                                                                         \
        if (pos < len) { STEP(fA0, pos) ++pos; }                                  \
        if (pos < len) { STEP(fA1, pos) ++pos; }                                  \
        if (pos < len) { STEP(fA2, pos) ++pos; }                                  \
        if (pos < len) { STEP(fA3, pos) ++pos; }                                  \
        if (pos < len) { STEP(fB0, pos) ++pos; }                                  \
        if (pos < len) { STEP(fB1, pos) ++pos; }                                  \
        if (pos < len) { STEP(fB2, pos) ++pos; }                                  \
    }

// value-match traceback step (ambient: j, jc, jr, trans_lds)
#define TB_STEP_G(PTR, TPOS, BVC, BVS, FS, OB, WSR, FB, K)                        \
    {                                                                             \
        float bvp_ = BVS[K];                                                      \
        float ap_ = bvp_ + FS[K];                                                 \
        float cand_ = ap_ + trans_lds[jr + PTR];                                  \
        float cm_ = (j < NT) ? cand_ : -3.0e38f;                                  \
        float tgt_ = __builtin_bit_cast(float,                                    \
            __builtin_amdgcn_readlane(__builtin_bit_cast(int, BVC), PTR));        \
        unsigned long long bm_ = __ballot(cm_ == tgt_);                           \
        PTR = __ffsll(bm_) - 1;                                                   \
        --TPOS;                                                                   \
        OB[TPOS] = PTR;                                                           \
        BVC = bvp_;                                                               \
        int rc_ = TPOS - 4; rc_ = rc_ < 0 ? 0 : rc_;                              \
        BVS[K] = WSR[(size_t)rc_ * 64 + j];                                       \
        FS[K] = FB[(size_t)rc_ * TT + jc];                                        \
    }

// ---------------- fast kernel -----------------------------------------------
__global__ __launch_bounds__(64, 1) void crf_viterbi_fast1(
    const float* __restrict__ feats,   // [B,S,T]
    const void*  __restrict__ mask,    // [B,S]
    const float* __restrict__ trans,   // [T,T]
    float* __restrict__ ws,            // [B,S,64] bv history (128 MiB)
    int* __restrict__ out)             // [B,S]
{
    __shared__ float trans_lds[64 * 53];            // [row i][col c], 53-padded
    __shared__ __align__(16) float a_sh[64];        // LDS-path alpha broadcast

    const int b = blockIdx.x;
    const int j = threadIdx.x;
    const int jc = j < NT ? j : NT - 1;
    const int jr = j * 53;

    // stage trans rows into LDS (traceback use); rows >= NT get -inf sentinel
    for (int k = j; k < 64 * 53; k += 64) {
        int r = k / 53, c = k - r * 53;
        float v = -3.0e38f;
        if (r < NT && c < TT) v = trans[r * TT + c];
        trans_lds[k] = v;
    }

    const int len = seq_len(mask, b, j);

    // init (pos 0): alpha0 = bv0 + f0 with bv0 = trans[START][j]
    const float* fp = feats + ((size_t)b * SS) * TT + jc;
    float* wsb = ws + ((size_t)b * SS) * 64 + j;
    const float bvi = trans[START_TAG * TT + jc];
    float alpha = bvi + fp[0];
    wsb[0] = bvi;

#if HAVE_SWAPS
    // ---- runtime calibration: push lane index through the exact gather ----
    float tt_[4][16];
    bool fastok;
    {
        int src_[4][16];
        unsigned pay = (unsigned)j;
        auto pp = __builtin_amdgcn_permlane32_swap(pay, pay, false, false);
        auto q0 = __builtin_amdgcn_permlane16_swap(pp[0], pp[0], false, false);
        auto q1 = __builtin_amdgcn_permlane16_swap(pp[1], pp[1], false, false);
        const int P0 = (int)q0[0], P1 = (int)q0[1], P2 = (int)q1[0], P3 = (int)q1[1];
        PROBE16(0, P0) PROBE16(1, P1) PROBE16(2, P2) PROBE16(3, P3)
        unsigned long long cov = 0;
#pragma unroll
        for (int r = 0; r < 4; ++r)
#pragma unroll
            for (int k = 0; k < 16; ++k) cov |= 1ull << src_[r][k];
        const unsigned long long need = (1ull << NT) - 1;
        bool ok = (cov & need) == need;
        fastok = (__ballot(ok) == ~0ull);
#pragma unroll
        for (int r = 0; r < 4; ++r)
#pragma unroll
            for (int k = 0; k < 16; ++k) {
                int i = src_[r][k];
                tt_[r][k] = (i < NT) ? trans[i * TT + j] : -3.0e38f;
            }
    }
    if (fastok) {
        FWD_LOOP(DP_STEP_FAST)
    } else
#endif
    {
        float tt[NT];
#pragma unroll
        for (int i = 0; i < NT; ++i) tt[i] = trans[i * TT + j];
        FWD_LOOP(DP_STEP_LDS)
    }

    // ---- best last tag ----
    float v = alpha + trans[jc * TT + STOP_TAG];
    if (j >= NT) v = -3.0e38f;
    int idxb = j < NT ? j : 0;
    for (int off = 32; off; off >>= 1) {
        float vo = __shfl_xor(v, off, 64);
        int   io = __shfl_xor(idxb, off, 64);
        if (vo > v || (vo == v && io < idxb)) { v = vo; idxb = io; }
    }

    __syncthreads();   // trans_lds visibility (one-time, cheap)

    // ---- traceback by value matching ----
    int ptr = idxb;
    int* ob = out + (size_t)b * SS;
    ob[len - 1] = ptr;

    const float* wsr = ws + ((size_t)b * SS) * 64;        // + r*64 + j
    const float* fbase = feats + ((size_t)b * SS) * TT;   // + r*TT + jc

    float bvs[4], fs[4];
    float bvc = wsr[(size_t)(len - 1) * 64 + j];
#pragma unroll
    for (int k = 0; k < 4; ++k) {
        int r = len - 2 - k; int rc = r < 0 ? 0 : r;
        bvs[k] = wsr[(size_t)rc * 64 + j];
        fs[k]  = fbase[(size_t)rc * TT + jc];
    }

    int tpos = len - 1;
    while (tpos >= 4) {
        TB_STEP_G(ptr, tpos, bvc, bvs, fs, ob, wsr, fbase, 0)
        TB_STEP_G(ptr, tpos, bvc, bvs, fs, ob, wsr, fbase, 1)
        TB_STEP_G(ptr, tpos, bvc, bvs, fs, ob, wsr, fbase, 2)
        TB_STEP_G(ptr, tpos, bvc, bvs, fs, ob, wsr, fbase, 3)
    }
    if (tpos >= 1) TB_STEP_G(ptr, tpos, bvc, bvs, fs, ob, wsr, fbase, 0)
    if (tpos >= 1) TB_STEP_G(ptr, tpos, bvc, bvs, fs, ob, wsr, fbase, 1)
    if (tpos >= 1) TB_STEP_G(ptr, tpos, bvc, bvs, fs, ob, wsr, fbase, 2)

    // zero-fill positions >= len
    for (int p = len + j; p < SS; p += 64) ob[p] = 0;
}

// ---------------- fallback (round-2 proven kernel, no workspace) ------------
__global__ __launch_bounds__(64, 1) void crf_viterbi(
    const float* __restrict__ feats,
    const void*  __restrict__ mask,
    const float* __restrict__ trans,
    int* __restrict__ out)
{
    __shared__ unsigned char bp_sh[SS * BPSTR];

    const int b = blockIdx.x;
    const int j = threadIdx.x;
    const int jc = j < NT ? j : NT - 1;

    const int len = seq_len(mask, b, j);

    float tt[NT];
#pragma unroll
    for (int i = 0; i < NT; ++i) tt[i] = trans[i * TT + j];

    const float* fp = feats + ((size_t)b * SS) * TT + jc;
    float alpha = trans[START_TAG * TT + jc] + fp[0];
    float fnext = fp[TT];

    for (int pos = 1; pos < len; ++pos) {
        const float f = fnext;
        { int np = pos + 1 < SS ? pos + 1 : SS - 1; fnext = fp[(size_t)np * TT]; }

        float best[4] = { -3.0e38f, -3.0e38f, -3.0e38f, -3.0e38f };
        int   bidx[4] = { 0, 0, 0, 0 };
        const int abits = __builtin_bit_cast(int, alpha);
#pragma unroll
        for (int i = 0; i < NT; ++i) {
            int ab = __builtin_amdgcn_readlane(abits, i);
            float s = __builtin_bit_cast(float, ab) + tt[i];
            const int c = i & 3;
            if (s > best[c]) { best[c] = s; bidx[c] = i; }
        }
        float bv = best[0]; int bi = bidx[0];
        if (best[1] > bv || (best[1] == bv && bidx[1] < bi)) { bv = best[1]; bi = bidx[1]; }
        if (best[2] > bv || (best[2] == bv && bidx[2] < bi)) { bv = best[2]; bi = bidx[2]; }
        if (best[3] > bv || (best[3] == bv && bidx[3] < bi)) { bv = best[3]; bi = bidx[3]; }

        alpha = bv + f;
        bp_sh[pos * BPSTR + j] = (unsigned char)bi;
    }

    float v = alpha + trans[jc * TT + STOP_TAG];
    if (j >= NT) v = -3.0e38f;
    int idx = j < NT ? j : 0;
    for (int off = 32; off; off >>= 1) {
        float vo = __shfl_xor(v, off, 64);
        int   io = __shfl_xor(idx, off, 64);
        if (vo > v || (vo == v && io < idx)) { v = vo; idx = io; }
    }

    __syncthreads();

    int ptr = idx;
    int* ob = out + (size_t)b * SS;
    for (int pos = len - 1; pos >= 1; --pos) {
        if (j == 0) ob[pos] = ptr;
        ptr = (int)bp_sh[pos * BPSTR + ptr];
    }
    if (j == 0) ob[0] = ptr;

    for (int p = len + j; p < SS; p += 64) ob[p] = 0;
}

extern "C" void kernel_launch(void* const* d_in, const int* in_sizes, int n_in,
                              void* d_out, int out_size, void* d_ws, size_t ws_size,
                              hipStream_t stream) {
    const float* feats = (const float*)d_in[0];
    const void*  mask  = d_in[1];
    // d_in[2] = tags, unused
    const float* trans = (const float*)d_in[3];
    int* out = (int*)d_out;

    const size_t need = (size_t)BB * SS * 64 * sizeof(float);   // 128 MiB
    if (ws_size >= need) {
        crf_viterbi_fast1<<<dim3(BB), dim3(64), 0, stream>>>(feats, mask, trans,
                                                             (float*)d_ws, out);
    } else {
        crf_viterbi<<<dim3(BB), dim3(64), 0, stream>>>(feats, mask, trans, out);
    }
}

// Round 16
// 184.080 us; speedup vs baseline: 1.0219x; 1.0219x over previous
//
#include <hip/hip_runtime.h>

#define TT 52          // tag count incl START/STOP
#define NT 50          // normal tags
#define START_TAG 50
#define STOP_TAG 51
#define BB 1024
#define SS 512
#define BPSTR 64       // fallback kernel LDS bp row stride

typedef __attribute__((__ext_vector_type__(2))) float f32x2;

__device__ __forceinline__ int seq_len(const void* mask, int b, int j) {
    int cnt = 0;
    const unsigned* w = (const unsigned*)mask;
    unsigned w0 = w[0];
    unsigned w1 = w[1];
    if (w0 == 0x01010101u) {                       // bool / uint8
        const unsigned char* m = (const unsigned char*)mask + (size_t)b * SS;
        for (int k = j; k < SS; k += 64) cnt += (m[k] != 0);
    } else if (w0 == 0x3f800000u) {                // float32
        const float* m = (const float*)mask + (size_t)b * SS;
        for (int k = j; k < SS; k += 64) cnt += (m[k] != 0.f);
    } else if (w1 == 1u) {                         // int32
        const int* m = (const int*)mask + (size_t)b * SS;
        for (int k = j; k < SS; k += 64) cnt += (m[k] != 0);
    } else {                                       // int64
        const long long* m = (const long long*)mask + (size_t)b * SS;
        for (int k = j; k < SS; k += 64) cnt += (m[k] != 0);
    }
    for (int off = 32; off; off >>= 1) cnt += __shfl_xor(cnt, off, 64);
    return cnt > 0 ? cnt : 1;
}

// S(k): k-th candidate score from the packed pairs
#define SEL(k) s2_[(k) >> 1][(k) & 1]

// One DP step (ambient: j, alpha, a_sh, tt2, wsb):
// LDS broadcast (1 ds_write_b32 + 13 broadcast ds_read_b128), 25 packed
// v_pk_add_f32 (two independent IEEE f32 adds each — identical rounding to
// the reference's scalar adds), exact max3 tree, store bv, alpha = bv + f.
// Double-buffered by step parity (compile-time constant in the unrolled
// body). bv/alpha bit-identical to the reference scan.
#define DP_STEP(FREG, POSV)                                                       \
    {                                                                             \
        a_sh[(POSV) & 1][j] = alpha;                                              \
        const float4* A4_ = (const float4*)a_sh[(POSV) & 1];                      \
        f32x2 s2_[25];                                                            \
        _Pragma("unroll")                                                         \
        for (int r_ = 0; r_ < 13; ++r_) {                                         \
            float4 t4_ = A4_[r_];                                                 \
            f32x2 lo_; lo_.x = t4_.x; lo_.y = t4_.y;                              \
            asm("v_pk_add_f32 %0, %1, %2"                                         \
                : "=v"(s2_[2 * r_]) : "v"(lo_), "v"(tt2[2 * r_]));                \
            if (2 * r_ + 1 < 25) {                                                \
                f32x2 hi_; hi_.x = t4_.z; hi_.y = t4_.w;                          \
                asm("v_pk_add_f32 %0, %1, %2"                                     \
                    : "=v"(s2_[2 * r_ + 1]) : "v"(hi_), "v"(tt2[2 * r_ + 1]));    \
            }                                                                     \
        }                                                                         \
        float m_[17];                                                             \
        _Pragma("unroll")                                                         \
        for (int k_ = 0; k_ < 16; ++k_)                                           \
            m_[k_] = fmaxf(fmaxf(SEL(3 * k_), SEL(3 * k_ + 1)), SEL(3 * k_ + 2)); \
        m_[16] = fmaxf(SEL(48), SEL(49));                                         \
        float n_[6];                                                              \
        _Pragma("unroll")                                                         \
        for (int k_ = 0; k_ < 5; ++k_)                                            \
            n_[k_] = fmaxf(fmaxf(m_[3 * k_], m_[3 * k_ + 1]), m_[3 * k_ + 2]);    \
        n_[5] = fmaxf(m_[15], m_[16]);                                            \
        float q0_ = fmaxf(fmaxf(n_[0], n_[1]), n_[2]);                            \
        float q1_ = fmaxf(fmaxf(n_[3], n_[4]), n_[5]);                            \
        float bv_ = fmaxf(q0_, q1_);                                              \
        wsb[(size_t)(POSV) * 64] = bv_;                                           \
        alpha = bv_ + (FREG);                                                     \
    }

// clamped feats load for lane's own tag (jc) at position p
#define FLD(P) fp[(size_t)((P) < SS ? (P) : SS - 1) * TT]

// value-match traceback step (ambient: j, jc, jr, trans_lds)
#define TB_STEP_G(PTR, TPOS, BVC, BVS, FS, OB, WSR, FB, K)                        \
    {                                                                             \
        float bvp_ = BVS[K];                                                      \
        float ap_ = bvp_ + FS[K];                                                 \
        float cand_ = ap_ + trans_lds[jr + PTR];                                  \
        float cm_ = (j < NT) ? cand_ : -3.0e38f;                                  \
        float tgt_ = __builtin_bit_cast(float,                                    \
            __builtin_amdgcn_readlane(__builtin_bit_cast(int, BVC), PTR));        \
        unsigned long long bm_ = __ballot(cm_ == tgt_);                           \
        PTR = __ffsll(bm_) - 1;                                                   \
        --TPOS;                                                                   \
        OB[TPOS] = PTR;                                                           \
        BVC = bvp_;                                                               \
        int rc_ = TPOS - 4; rc_ = rc_ < 0 ? 0 : rc_;                              \
        BVS[K] = WSR[(size_t)rc_ * 64 + j];                                       \
        FS[K] = FB[(size_t)rc_ * TT + jc];                                        \
    }

// ---------------- fast kernel: LDS-broadcast + pk_add fwd; value-match tb ---
__global__ __launch_bounds__(64, 1) void crf_viterbi_fast1(
    const float* __restrict__ feats,   // [B,S,T]
    const void*  __restrict__ mask,    // [B,S]
    const float* __restrict__ trans,   // [T,T]
    float* __restrict__ ws,            // [B,S,64] bv history (128 MiB)
    int* __restrict__ out)             // [B,S]
{
    __shared__ float trans_lds[64 * 53];                 // [row i][col c], 53-padded
    __shared__ __align__(16) float a_sh[2][64];          // alpha broadcast, dbuf

    const int b = blockIdx.x;
    const int j = threadIdx.x;
    const int jc = j < NT ? j : NT - 1;
    const int jr = j * 53;

    // stage trans rows into LDS (traceback use); rows >= NT get -inf sentinel
    for (int k = j; k < 64 * 53; k += 64) {
        int r = k / 53, c = k - r * 53;
        float v = -3.0e38f;
        if (r < NT && c < TT) v = trans[r * TT + c];
        trans_lds[k] = v;
    }

    const int len = seq_len(mask, b, j);

    // transition column trans[0..49][j] as 25 aligned pairs (sources 0..49)
    f32x2 tt2[25];
#pragma unroll
    for (int p = 0; p < 25; ++p) {
        tt2[p].x = trans[(2 * p) * TT + j];       // idx <= 49*52+63 = 2611 < 2704
        tt2[p].y = trans[(2 * p + 1) * TT + j];
    }

    // init (pos 0): alpha0 = bv0 + f0 with bv0 = trans[START][j]
    const float* fp = feats + ((size_t)b * SS) * TT + jc;
    float* wsb = ws + ((size_t)b * SS) * 64 + j;
    const float bvi = trans[START_TAG * TT + jc];
    float alpha = bvi + fp[0];
    wsb[0] = bvi;

    // ---- forward with 8-deep feats prefetch (two named 4-reg groups) ----
    // Invariant at loop top: fA = f[pos..pos+3], fB = f[pos+4..pos+7]
    float fA0 = FLD(1), fA1 = FLD(2), fA2 = FLD(3), fA3 = FLD(4);
    float fB0 = FLD(5), fB1 = FLD(6), fB2 = FLD(7), fB3 = FLD(8);

    int pos = 1;
    for (; pos + 7 < len; pos += 8) {
        DP_STEP(fA0, pos + 0)
        DP_STEP(fA1, pos + 1)
        DP_STEP(fA2, pos + 2)
        DP_STEP(fA3, pos + 3)
        fA0 = FLD(pos + 8);  fA1 = FLD(pos + 9);
        fA2 = FLD(pos + 10); fA3 = FLD(pos + 11);
        DP_STEP(fB0, pos + 4)
        DP_STEP(fB1, pos + 5)
        DP_STEP(fB2, pos + 6)
        DP_STEP(fB3, pos + 7)
        fB0 = FLD(pos + 12); fB1 = FLD(pos + 13);
        fB2 = FLD(pos + 14); fB3 = FLD(pos + 15);
    }
    // tail: fA = f[pos..pos+3], fB = f[pos+4..pos+7]; up to 7 steps remain
    if (pos < len) { DP_STEP(fA0, pos) ++pos; }
    if (pos < len) { DP_STEP(fA1, pos) ++pos; }
    if (pos < len) { DP_STEP(fA2, pos) ++pos; }
    if (pos < len) { DP_STEP(fA3, pos) ++pos; }
    if (pos < len) { DP_STEP(fB0, pos) ++pos; }
    if (pos < len) { DP_STEP(fB1, pos) ++pos; }
    if (pos < len) { DP_STEP(fB2, pos) ++pos; }

    // ---- best last tag ----
    float v = alpha + trans[jc * TT + STOP_TAG];
    if (j >= NT) v = -3.0e38f;
    int idxb = j < NT ? j : 0;
    for (int off = 32; off; off >>= 1) {
        float vo = __shfl_xor(v, off, 64);
        int   io = __shfl_xor(idxb, off, 64);
        if (vo > v || (vo == v && io < idxb)) { v = vo; idxb = io; }
    }

    __syncthreads();   // trans_lds visibility (one-time, cheap)

    // ---- traceback by value matching ----
    int ptr = idxb;
    int* ob = out + (size_t)b * SS;
    ob[len - 1] = ptr;

    const float* wsr = ws + ((size_t)b * SS) * 64;        // + r*64 + j
    const float* fbase = feats + ((size_t)b * SS) * TT;   // + r*TT + jc

    float bvs[4], fs[4];
    float bvc = wsr[(size_t)(len - 1) * 64 + j];
#pragma unroll
    for (int k = 0; k < 4; ++k) {
        int r = len - 2 - k; int rc = r < 0 ? 0 : r;
        bvs[k] = wsr[(size_t)rc * 64 + j];
        fs[k]  = fbase[(size_t)rc * TT + jc];
    }

    int tpos = len - 1;
    while (tpos >= 4) {
        TB_STEP_G(ptr, tpos, bvc, bvs, fs, ob, wsr, fbase, 0)
        TB_STEP_G(ptr, tpos, bvc, bvs, fs, ob, wsr, fbase, 1)
        TB_STEP_G(ptr, tpos, bvc, bvs, fs, ob, wsr, fbase, 2)
        TB_STEP_G(ptr, tpos, bvc, bvs, fs, ob, wsr, fbase, 3)
    }
    if (tpos >= 1) TB_STEP_G(ptr, tpos, bvc, bvs, fs, ob, wsr, fbase, 0)
    if (tpos >= 1) TB_STEP_G(ptr, tpos, bvc, bvs, fs, ob, wsr, fbase, 1)
    if (tpos >= 1) TB_STEP_G(ptr, tpos, bvc, bvs, fs, ob, wsr, fbase, 2)

    // zero-fill positions >= len
    for (int p = len + j; p < SS; p += 64) ob[p] = 0;
}

// ---------------- fallback (round-2 proven kernel, no workspace) ------------
__global__ __launch_bounds__(64, 1) void crf_viterbi(
    const float* __restrict__ feats,
    const void*  __restrict__ mask,
    const float* __restrict__ trans,
    int* __restrict__ out)
{
    __shared__ unsigned char bp_sh[SS * BPSTR];

    const int b = blockIdx.x;
    const int j = threadIdx.x;
    const int jc = j < NT ? j : NT - 1;

    const int len = seq_len(mask, b, j);

    float tt[NT];
#pragma unroll
    for (int i = 0; i < NT; ++i) tt[i] = trans[i * TT + j];

    const float* fp = feats + ((size_t)b * SS) * TT + jc;
    float alpha = trans[START_TAG * TT + jc] + fp[0];
    float fnext = fp[TT];

    for (int pos = 1; pos < len; ++pos) {
        const float f = fnext;
        { int np = pos + 1 < SS ? pos + 1 : SS - 1; fnext = fp[(size_t)np * TT]; }

        float best[4] = { -3.0e38f, -3.0e38f, -3.0e38f, -3.0e38f };
        int   bidx[4] = { 0, 0, 0, 0 };
        const int abits = __builtin_bit_cast(int, alpha);
#pragma unroll
        for (int i = 0; i < NT; ++i) {
            int ab = __builtin_amdgcn_readlane(abits, i);
            float s = __builtin_bit_cast(float, ab) + tt[i];
            const int c = i & 3;
            if (s > best[c]) { best[c] = s; bidx[c] = i; }
        }
        float bv = best[0]; int bi = bidx[0];
        if (best[1] > bv || (best[1] == bv && bidx[1] < bi)) { bv = best[1]; bi = bidx[1]; }
        if (best[2] > bv || (best[2] == bv && bidx[2] < bi)) { bv = best[2]; bi = bidx[2]; }
        if (best[3] > bv || (best[3] == bv && bidx[3] < bi)) { bv = best[3]; bi = bidx[3]; }

        alpha = bv + f;
        bp_sh[pos * BPSTR + j] = (unsigned char)bi;
    }

    float v = alpha + trans[jc * TT + STOP_TAG];
    if (j >= NT) v = -3.0e38f;
    int idx = j < NT ? j : 0;
    for (int off = 32; off; off >>= 1) {
        float vo = __shfl_xor(v, off, 64);
        int   io = __shfl_xor(idx, off, 64);
        if (vo > v || (vo == v && io < idx)) { v = vo; idx = io; }
    }

    __syncthreads();

    int ptr = idx;
    int* ob = out + (size_t)b * SS;
    for (int pos = len - 1; pos >= 1; --pos) {
        if (j == 0) ob[pos] = ptr;
        ptr = (int)bp_sh[pos * BPSTR + ptr];
    }
    if (j == 0) ob[0] = ptr;

    for (int p = len + j; p < SS; p += 64) ob[p] = 0;
}

extern "C" void kernel_launch(void* const* d_in, const int* in_sizes, int n_in,
                              void* d_out, int out_size, void* d_ws, size_t ws_size,
                              hipStream_t stream) {
    const float* feats = (const float*)d_in[0];
    const void*  mask  = d_in[1];
    // d_in[2] = tags, unused
    const float* trans = (const float*)d_in[3];
    int* out = (int*)d_out;

    const size_t need = (size_t)BB * SS * 64 * sizeof(float);   // 128 MiB
    if (ws_size >= need) {
        crf_viterbi_fast1<<<dim3(BB), dim3(64), 0, stream>>>(feats, mask, trans,
                                                             (float*)d_ws, out);
    } else {
        crf_viterbi<<<dim3(BB), dim3(64), 0, stream>>>(feats, mask, trans, out);
    }
}

// Round 17
// 170.780 us; speedup vs baseline: 1.1015x; 1.0779x over previous
//
#include <hip/hip_runtime.h>

#define TT 52          // tag count incl START/STOP
#define NT 50          // normal tags
#define START_TAG 50
#define STOP_TAG 51
#define BB 1024
#define SS 512
#define BPSTR 64       // fallback kernel LDS bp row stride

__device__ __forceinline__ int seq_len(const void* mask, int b, int j) {
    int cnt = 0;
    const unsigned* w = (const unsigned*)mask;
    unsigned w0 = w[0];
    unsigned w1 = w[1];
    if (w0 == 0x01010101u) {                       // bool / uint8
        const unsigned char* m = (const unsigned char*)mask + (size_t)b * SS;
        for (int k = j; k < SS; k += 64) cnt += (m[k] != 0);
    } else if (w0 == 0x3f800000u) {                // float32
        const float* m = (const float*)mask + (size_t)b * SS;
        for (int k = j; k < SS; k += 64) cnt += (m[k] != 0.f);
    } else if (w1 == 1u) {                         // int32
        const int* m = (const int*)mask + (size_t)b * SS;
        for (int k = j; k < SS; k += 64) cnt += (m[k] != 0);
    } else {                                       // int64
        const long long* m = (const long long*)mask + (size_t)b * SS;
        for (int k = j; k < SS; k += 64) cnt += (m[k] != 0);
    }
    for (int off = 32; off; off >>= 1) cnt += __shfl_xor(cnt, off, 64);
    return cnt > 0 ? cnt : 1;
}

// One DP step: broadcast alpha via LDS (1 ds_write_b32 + 13 broadcast
// ds_read_b128, conflict-free), 50 scalar adds, exact max3 tree (v_max3),
// store bv, alpha = bv + f. No barrier (single wave; DS pipe is in-order;
// compiler emits fine-grained lgkmcnt). Double-buffered by step parity
// (compile-time constant in the unroll-8 body). Bit-identical math to the
// reference scan (same f32 adds, exact order-independent max).
#define DP_STEP(FREG, POSV)                                                       \
    {                                                                             \
        a_sh[(POSV) & 1][j] = alpha;                                              \
        float q_[52];                                                             \
        _Pragma("unroll")                                                         \
        for (int r_ = 0; r_ < 13; ++r_) {                                         \
            float4 t4_ = ((const float4*)a_sh[(POSV) & 1])[r_];                   \
            q_[4 * r_ + 0] = t4_.x; q_[4 * r_ + 1] = t4_.y;                       \
            q_[4 * r_ + 2] = t4_.z; q_[4 * r_ + 3] = t4_.w;                       \
        }                                                                         \
        float s_[NT];                                                             \
        _Pragma("unroll")                                                         \
        for (int i_ = 0; i_ < NT; ++i_) s_[i_] = q_[i_] + tt[i_];                 \
        float m_[17];                                                             \
        _Pragma("unroll")                                                         \
        for (int k_ = 0; k_ < 16; ++k_)                                           \
            m_[k_] = fmaxf(fmaxf(s_[3 * k_], s_[3 * k_ + 1]), s_[3 * k_ + 2]);    \
        m_[16] = fmaxf(s_[48], s_[49]);                                           \
        float n_[6];                                                              \
        _Pragma("unroll")                                                         \
        for (int k_ = 0; k_ < 5; ++k_)                                            \
            n_[k_] = fmaxf(fmaxf(m_[3 * k_], m_[3 * k_ + 1]), m_[3 * k_ + 2]);    \
        n_[5] = fmaxf(m_[15], m_[16]);                                            \
        float q0_ = fmaxf(fmaxf(n_[0], n_[1]), n_[2]);                            \
        float q1_ = fmaxf(fmaxf(n_[3], n_[4]), n_[5]);                            \
        float bv_ = fmaxf(q0_, q1_);                                              \
        wsb[(size_t)(POSV) * 64] = bv_;                                           \
        alpha = bv_ + (FREG);                                                     \
    }

// clamped feats load for lane's own tag (jc) at position p
#define FLD(P) fp[(size_t)((P) < SS ? (P) : SS - 1) * TT]

// ---------------- fast kernel: LDS-broadcast fwd; value-match traceback -----
__global__ __launch_bounds__(64, 1) void crf_viterbi_fast1(
    const float* __restrict__ feats,   // [B,S,T]
    const void*  __restrict__ mask,    // [B,S]
    const float* __restrict__ trans,   // [T,T]
    float* __restrict__ ws,            // [B,S,64] bv history (128 MiB)
    int* __restrict__ out)             // [B,S]
{
    __shared__ float trans_lds[64 * 53];                    // [row i][col c], 53-padded
    __shared__ __align__(16) float a_sh[2][64];             // alpha broadcast, dbuf by parity

    const int b = blockIdx.x;
    const int j = threadIdx.x;
    const int jc = j < NT ? j : NT - 1;
    const int jr = j * 53;

    // stage trans rows into LDS; rows >= NT get -inf sentinel
    for (int k = j; k < 64 * 53; k += 64) {
        int r = k / 53, c = k - r * 53;
        float v = -3.0e38f;
        if (r < NT && c < TT) v = trans[r * TT + c];
        trans_lds[k] = v;
    }

    const int len = seq_len(mask, b, j);

    // transition column trans[0..49][j] into registers
    float tt[NT];
#pragma unroll
    for (int i = 0; i < NT; ++i) tt[i] = trans[i * TT + j];  // j<=63: in bounds (2611<2704)

    // init (pos 0): alpha0 = bv0 + f0 with bv0 = trans[START][j]
    const float* fp = feats + ((size_t)b * SS) * TT + jc;
    float* wsb = ws + ((size_t)b * SS) * 64 + j;
    const float bv0 = trans[START_TAG * TT + jc];
    float alpha = bv0 + fp[0];
    wsb[0] = bv0;

    // ---- forward with 8-deep feats prefetch (two named 4-reg groups) ----
    // Invariant at loop top: fA = f[pos..pos+3], fB = f[pos+4..pos+7]
    float fA0 = FLD(1), fA1 = FLD(2), fA2 = FLD(3), fA3 = FLD(4);
    float fB0 = FLD(5), fB1 = FLD(6), fB2 = FLD(7), fB3 = FLD(8);

    int pos = 1;
    for (; pos + 7 < len; pos += 8) {
        DP_STEP(fA0, pos + 0)
        DP_STEP(fA1, pos + 1)
        DP_STEP(fA2, pos + 2)
        DP_STEP(fA3, pos + 3)
        fA0 = FLD(pos + 8);  fA1 = FLD(pos + 9);
        fA2 = FLD(pos + 10); fA3 = FLD(pos + 11);
        DP_STEP(fB0, pos + 4)
        DP_STEP(fB1, pos + 5)
        DP_STEP(fB2, pos + 6)
        DP_STEP(fB3, pos + 7)
        fB0 = FLD(pos + 12); fB1 = FLD(pos + 13);
        fB2 = FLD(pos + 14); fB3 = FLD(pos + 15);
    }
    // tail: fA = f[pos..pos+3], fB = f[pos+4..pos+7]; up to 7 steps remain
    if (pos < len) { DP_STEP(fA0, pos) ++pos; }
    if (pos < len) { DP_STEP(fA1, pos) ++pos; }
    if (pos < len) { DP_STEP(fA2, pos) ++pos; }
    if (pos < len) { DP_STEP(fA3, pos) ++pos; }
    if (pos < len) { DP_STEP(fB0, pos) ++pos; }
    if (pos < len) { DP_STEP(fB1, pos) ++pos; }
    if (pos < len) { DP_STEP(fB2, pos) ++pos; }

    // ---- best last tag ----
    float v = alpha + trans[jc * TT + STOP_TAG];
    if (j >= NT) v = -3.0e38f;
    int idxb = j < NT ? j : 0;
    for (int off = 32; off; off >>= 1) {
        float vo = __shfl_xor(v, off, 64);
        int   io = __shfl_xor(idxb, off, 64);
        if (vo > v || (vo == v && io < idxb)) { v = vo; idxb = io; }
    }

    __syncthreads();   // one-time; trans_lds visibility before traceback

    // ---- traceback by value matching ----
    int ptr = idxb;
    int* ob = out + (size_t)b * SS;
    ob[len - 1] = ptr;

    const float* wsr = ws + ((size_t)b * SS) * 64;        // + r*64 + j
    const float* fbase = feats + ((size_t)b * SS) * TT;   // + r*TT + jc

    float bvs[4], fs[4];
    float bv_cur;
    {
        int r0 = len - 1;
        bv_cur = wsr[(size_t)r0 * 64 + j];
#pragma unroll
        for (int k = 0; k < 4; ++k) {
            int r = len - 2 - k; int rc = r < 0 ? 0 : r;
            bvs[k] = wsr[(size_t)rc * 64 + j];
            fs[k]  = fbase[(size_t)rc * TT + jc];
        }
    }

    int tpos = len - 1;

#define TB_STEP(k)                                                              \
    {                                                                           \
        float bv_prev = bvs[k];                                                 \
        float alpha_prev = bv_prev + fs[k];                                     \
        float cand = alpha_prev + trans_lds[jr + ptr];                          \
        float candm = (j < NT) ? cand : -3.0e38f;                               \
        float tgt = __builtin_bit_cast(float,                                   \
            __builtin_amdgcn_readlane(__builtin_bit_cast(int, bv_cur), ptr));   \
        unsigned long long bm = __ballot(candm == tgt);                         \
        ptr = __ffsll(bm) - 1;                                                  \
        --tpos;                                                                 \
        ob[tpos] = ptr;                                                         \
        bv_cur = bv_prev;                                                       \
        int rc = tpos - 4; rc = rc < 0 ? 0 : rc;                                \
        bvs[k] = wsr[(size_t)rc * 64 + j];                                      \
        fs[k]  = fbase[(size_t)rc * TT + jc];                                   \
    }

    while (tpos >= 4) {
        TB_STEP(0) TB_STEP(1) TB_STEP(2) TB_STEP(3)
    }
#pragma unroll
    for (int k = 0; k < 3; ++k) {
        if (tpos >= 1) TB_STEP(k)
    }
#undef TB_STEP

    // zero-fill positions >= len
    for (int p = len + j; p < SS; p += 64) ob[p] = 0;
}

// ---------------- fallback (round-2 proven kernel, no workspace) ------------
__global__ __launch_bounds__(64, 1) void crf_viterbi(
    const float* __restrict__ feats,
    const void*  __restrict__ mask,
    const float* __restrict__ trans,
    int* __restrict__ out)
{
    __shared__ unsigned char bp_sh[SS * BPSTR];

    const int b = blockIdx.x;
    const int j = threadIdx.x;
    const int jc = j < NT ? j : NT - 1;

    const int len = seq_len(mask, b, j);

    float tt[NT];
#pragma unroll
    for (int i = 0; i < NT; ++i) tt[i] = trans[i * TT + j];

    const float* fp = feats + ((size_t)b * SS) * TT + jc;
    float alpha = trans[START_TAG * TT + jc] + fp[0];
    float fnext = fp[TT];

    for (int pos = 1; pos < len; ++pos) {
        const float f = fnext;
        { int np = pos + 1 < SS ? pos + 1 : SS - 1; fnext = fp[(size_t)np * TT]; }

        float best[4] = { -3.0e38f, -3.0e38f, -3.0e38f, -3.0e38f };
        int   bidx[4] = { 0, 0, 0, 0 };
        const int abits = __builtin_bit_cast(int, alpha);
#pragma unroll
        for (int i = 0; i < NT; ++i) {
            int ab = __builtin_amdgcn_readlane(abits, i);
            float s = __builtin_bit_cast(float, ab) + tt[i];
            const int c = i & 3;
            if (s > best[c]) { best[c] = s; bidx[c] = i; }
        }
        float bv = best[0]; int bi = bidx[0];
        if (best[1] > bv || (best[1] == bv && bidx[1] < bi)) { bv = best[1]; bi = bidx[1]; }
        if (best[2] > bv || (best[2] == bv && bidx[2] < bi)) { bv = best[2]; bi = bidx[2]; }
        if (best[3] > bv || (best[3] == bv && bidx[3] < bi)) { bv = best[3]; bi = bidx[3]; }

        alpha = bv + f;
        bp_sh[pos * BPSTR + j] = (unsigned char)bi;
    }

    float v = alpha + trans[jc * TT + STOP_TAG];
    if (j >= NT) v = -3.0e38f;
    int idx = j < NT ? j : 0;
    for (int off = 32; off; off >>= 1) {
        float vo = __shfl_xor(v, off, 64);
        int   io = __shfl_xor(idx, off, 64);
        if (vo > v || (vo == v && io < idx)) { v = vo; idx = io; }
    }

    __syncthreads();

    int ptr = idx;
    int* ob = out + (size_t)b * SS;
    for (int pos = len - 1; pos >= 1; --pos) {
        if (j == 0) ob[pos] = ptr;
        ptr = (int)bp_sh[pos * BPSTR + ptr];
    }
    if (j == 0) ob[0] = ptr;

    for (int p = len + j; p < SS; p += 64) ob[p] = 0;
}

extern "C" void kernel_launch(void* const* d_in, const int* in_sizes, int n_in,
                              void* d_out, int out_size, void* d_ws, size_t ws_size,
                              hipStream_t stream) {
    const float* feats = (const float*)d_in[0];
    const void*  mask  = d_in[1];
    // d_in[2] = tags, unused
    const float* trans = (const float*)d_in[3];
    int* out = (int*)d_out;

    const size_t need = (size_t)BB * SS * 64 * sizeof(float);   // 128 MiB
    if (ws_size >= need) {
        crf_viterbi_fast1<<<dim3(BB), dim3(64), 0, stream>>>(feats, mask, trans,
                                                             (float*)d_ws, out);
    } else {
        crf_viterbi<<<dim3(BB), dim3(64), 0, stream>>>(feats, mask, trans, out);
    }
}